// Round 4
// baseline (32.221 us; speedup 1.0000x reference)
//
#include <hip/hip_runtime.h>
#include <hip/hip_bf16.h>

#define HID 16
#define DIN 64
#define NK  32
#define NB  8192

typedef float v2f __attribute__((ext_vector_type(2)));
typedef float v4f __attribute__((ext_vector_type(4)));

struct W {
    v2f w1[8], b1[8], w2[8];   // h-pairs, per-lane (lane = d)
};

// Inner MLP for one batch row, this lane's d: sum_h relu(x*w1+b1)*w2
__device__ __forceinline__ float relu_dot(const W& w, float xd) {
    const v2f xx = {xd, xd};
    v2f acc0 = {0.f, 0.f}, acc1 = {0.f, 0.f};
    #pragma unroll
    for (int hp = 0; hp < 8; hp += 2) {
        v2f t0 = __builtin_elementwise_fma(xx, w.w1[hp],     w.b1[hp]);
        v2f t1 = __builtin_elementwise_fma(xx, w.w1[hp + 1], w.b1[hp + 1]);
        t0 = __builtin_elementwise_max(t0, (v2f){0.f, 0.f});
        t1 = __builtin_elementwise_max(t1, (v2f){0.f, 0.f});
        acc0 = __builtin_elementwise_fma(t0, w.w2[hp],     acc0);
        acc1 = __builtin_elementwise_fma(t1, w.w2[hp + 1], acc1);
    }
    const v2f a = acc0 + acc1;
    return a.x + a.y;
}

// Merge two level-(LVL-1) partial blocks at XOR distance m = 64>>LVL.
// After the full tree, lane L holds the complete d-sum for slot rev6(L).
template<int LVL, class F>
__device__ __forceinline__ float subtree(int j0, int lane, const F& body) {
    if constexpr (LVL == 0) {
        return body(j0);
    } else {
        const float A = subtree<LVL - 1>(j0, lane, body);
        const float B = subtree<LVL - 1>(j0 + (1 << (LVL - 1)), lane, body);
        const int m = 64 >> LVL;
        const bool hi = (lane & m) != 0;
        const float send = hi ? A : B;
        const float recv = __shfl_xor(send, m, 64);
        const float keep = hi ? B : A;
        return keep + recv;
    }
}

// lane = d (64 lanes = DIN). Weights VGPR-resident, loaded once per wave.
// Each wave: one k, one 64-row batch. Inner loop is pure packed VALU.
__global__ __launch_bounds__(256, 4) void kan_kernel(
    const float* __restrict__ x,
    const float* __restrict__ iw1, const float* __restrict__ ib1,
    const float* __restrict__ iw2, const float* __restrict__ ib2,
    const float* __restrict__ ow1, const float* __restrict__ ob1,
    const float* __restrict__ ow2, const float* __restrict__ ob2,
    float* __restrict__ out)
{
    const int k     = blockIdx.x & (NK - 1);
    const int chunk = blockIdx.x >> 5;           // 32 chunks of 256 rows
    const int t     = threadIdx.x;
    const int lane  = t & 63;
    const int wid   = t >> 6;
    const int base  = chunk * 256 + wid * 64;    // this wave's 64 rows

    // Per-lane weight load (lane = d): 16 consecutive floats per array.
    W w;
    {
        const v4f* p1 = (const v4f*)(iw1 + (k * DIN + lane) * HID);
        const v4f* p2 = (const v4f*)(ib1 + (k * DIN + lane) * HID);
        const v4f* p3 = (const v4f*)(iw2 + (k * DIN + lane) * HID);
        #pragma unroll
        for (int q = 0; q < 4; ++q) {
            ((v4f*)w.w1)[q] = p1[q];
            ((v4f*)w.b1)[q] = p2[q];
            ((v4f*)w.w2)[q] = p3[q];
        }
    }

    // C_k = sum_d ib2[k,d] (same for every row; full wave reduce once)
    float ck = ib2[k * DIN + lane];
    #pragma unroll
    for (int m = 32; m; m >>= 1) ck += __shfl_xor(ck, m, 64);

    const float* __restrict__ xp = x + base * DIN + lane;
    auto body = [&](int j) { return relu_dot(w, xp[j * DIN]); };

    const float sk = subtree<6>(0, lane, body) + ck;

    // Outer net, lane-parallel (this lane's row): scalar -> 16 -> scalar
    float o = ob2[k];
    #pragma unroll
    for (int h = 0; h < HID; ++h) {
        const float g = fmaxf(fmaf(sk, ow1[k * HID + h], ob1[k * HID + h]), 0.f);
        o = fmaf(g, ow2[k * HID + h], o);
    }

    const int brev = (int)(__builtin_bitreverse32((unsigned)lane) >> 26);
    out[(base + brev) * NK + k] = o;
}

extern "C" void kernel_launch(void* const* d_in, const int* in_sizes, int n_in,
                              void* d_out, int out_size, void* d_ws, size_t ws_size,
                              hipStream_t stream) {
    const float* x   = (const float*)d_in[0];
    const float* iw1 = (const float*)d_in[1];
    const float* ib1 = (const float*)d_in[2];
    const float* iw2 = (const float*)d_in[3];
    const float* ib2 = (const float*)d_in[4];
    const float* ow1 = (const float*)d_in[5];
    const float* ob1 = (const float*)d_in[6];
    const float* ow2 = (const float*)d_in[7];
    const float* ob2 = (const float*)d_in[8];
    float* out = (float*)d_out;

    const int grid = (NB / 256) * NK;  // 32 * 32 = 1024 blocks
    kan_kernel<<<grid, 256, 0, stream>>>(x, iw1, ib1, iw2, ib2,
                                         ow1, ob1, ow2, ob2, out);
}

// Round 5
// 26.489 us; speedup vs baseline: 1.2164x; 1.2164x over previous
//
#include <hip/hip_runtime.h>
#include <hip/hip_bf16.h>

#define HID 16
#define DIN 64
#define NK  32
#define NB  8192

typedef float v2f __attribute__((ext_vector_type(2)));
typedef float v4f __attribute__((ext_vector_type(4)));

struct W {
    v2f w1[8], b1[8], w2[8];   // h-pairs, per-lane (lane = d)
};

// Inner MLP for one batch row, this lane's d: sum_h relu(x*w1+b1)*w2
__device__ __forceinline__ float relu_dot(const W& w, float xd) {
    const v2f xx = {xd, xd};
    v2f acc0 = {0.f, 0.f}, acc1 = {0.f, 0.f};
    #pragma unroll
    for (int hp = 0; hp < 8; hp += 2) {
        v2f t0 = __builtin_elementwise_fma(xx, w.w1[hp],     w.b1[hp]);
        v2f t1 = __builtin_elementwise_fma(xx, w.w1[hp + 1], w.b1[hp + 1]);
        t0 = __builtin_elementwise_max(t0, (v2f){0.f, 0.f});
        t1 = __builtin_elementwise_max(t1, (v2f){0.f, 0.f});
        acc0 = __builtin_elementwise_fma(t0, w.w2[hp],     acc0);
        acc1 = __builtin_elementwise_fma(t1, w.w2[hp + 1], acc1);
    }
    const v2f a = acc0 + acc1;
    return a.x + a.y;
}

// lane = d. Weights VGPR-resident. Per-wave LDS transpose for the d-sum:
// write lds[d][row] (stride 17 -> 2-way bank alias = free), read along d.
// 4 passes x 16 rows keeps unroll small -> no spills.
__global__ __launch_bounds__(256, 4) void kan_kernel(
    const float* __restrict__ x,
    const float* __restrict__ iw1, const float* __restrict__ ib1,
    const float* __restrict__ iw2, const float* __restrict__ ib2,
    const float* __restrict__ ow1, const float* __restrict__ ob1,
    const float* __restrict__ ow2, const float* __restrict__ ob2,
    float* __restrict__ out)
{
    __shared__ float lds[4][DIN * 17];

    const int t    = threadIdx.x;
    const int lane = t & 63;
    const int wid  = t >> 6;
    const int k    = blockIdx.x & (NK - 1);
    const int base = ((blockIdx.x >> 5) * 4 + wid) * 64;   // this wave's 64 rows

    // Per-lane weight load (lane = d): 48 VGPRs, once per wave.
    W w;
    {
        const v4f* p1 = (const v4f*)(iw1 + (k * DIN + lane) * HID);
        const v4f* p2 = (const v4f*)(ib1 + (k * DIN + lane) * HID);
        const v4f* p3 = (const v4f*)(iw2 + (k * DIN + lane) * HID);
        #pragma unroll
        for (int q = 0; q < 4; ++q) {
            ((v4f*)w.w1)[q] = p1[q];
            ((v4f*)w.b1)[q] = p2[q];
            ((v4f*)w.w2)[q] = p3[q];
        }
    }

    // ck = sum_d ib2[k,d] (row-independent), full wave reduce once.
    float ck = ib2[k * DIN + lane];
    #pragma unroll
    for (int m = 32; m; m >>= 1) ck += __shfl_xor(ck, m, 64);

    float* __restrict__ myLds = lds[wid];
    const float* __restrict__ xp = x + base * DIN + lane;

    const int jj = lane & 15;   // row slot this lane reduces
    const int p  = lane >> 4;   // which 16 d's this lane sums

    float rsum[4];

    #pragma unroll
    for (int pass = 0; pass < 4; ++pass) {
        const float* __restrict__ xq = xp + pass * 16 * DIN;
        #pragma unroll
        for (int j = 0; j < 16; ++j) {
            myLds[lane * 17 + j] = relu_dot(w, xq[j * DIN]);
        }
        __builtin_amdgcn_sched_barrier(0);   // keep writes before reads
        float s = 0.f;
        #pragma unroll
        for (int i = 0; i < 16; ++i) {
            s += myLds[(p * 16 + i) * 17 + jj];
        }
        __builtin_amdgcn_sched_barrier(0);   // keep reads before next writes
        s += __shfl_xor(s, 16, 64);
        s += __shfl_xor(s, 32, 64);
        rsum[pass] = s + ck;
    }

    // Lane l owns row base+l: pass index = l>>4, static select.
    const float sk = (lane & 32) ? ((lane & 16) ? rsum[3] : rsum[2])
                                 : ((lane & 16) ? rsum[1] : rsum[0]);

    // Outer net: scalar -> HID -> scalar (per k)
    float o = ob2[k];
    #pragma unroll
    for (int h = 0; h < HID; ++h) {
        const float g = fmaxf(fmaf(sk, ow1[k * HID + h], ob1[k * HID + h]), 0.f);
        o = fmaf(g, ow2[k * HID + h], o);
    }

    out[(base + lane) * NK + k] = o;
}

extern "C" void kernel_launch(void* const* d_in, const int* in_sizes, int n_in,
                              void* d_out, int out_size, void* d_ws, size_t ws_size,
                              hipStream_t stream) {
    const float* x   = (const float*)d_in[0];
    const float* iw1 = (const float*)d_in[1];
    const float* ib1 = (const float*)d_in[2];
    const float* iw2 = (const float*)d_in[3];
    const float* ib2 = (const float*)d_in[4];
    const float* ow1 = (const float*)d_in[5];
    const float* ob1 = (const float*)d_in[6];
    const float* ow2 = (const float*)d_in[7];
    const float* ob2 = (const float*)d_in[8];
    float* out = (float*)d_out;

    const int grid = (NB / 256) * NK;  // 32 chunks * 32 k = 1024 blocks, 4 waves each
    kan_kernel<<<grid, 256, 0, stream>>>(x, iw1, ib1, iw2, ib2,
                                         ow1, ob1, ow2, ob2, out);
}